// Round 12
// baseline (2001.682 us; speedup 1.0000x reference)
//
#include <hip/hip_runtime.h>

// ---------------------------------------------------------------------------
// HeteroFraudGNN on MI355X — round 12: wave-autonomous fused kernel (zero
// intra-loop barriers). Every round's latency loss traced to the per-tile
// block barrier coupling all waves to the slowest gather. Fix: each WAVE owns
// a 16-row tile end-to-end — lane l gathers row base+(l&15), cols
// (l>>4)*8+{0..7}+{0,32,64,96} straight into facc[32] (fp32), which IS the
// MFMA A-fragment set after fp16 convert. No sA, no handoff, no barrier.
//   once per block: sB=[Wr|Wl] 64KB swizzled; one barrier; then waves
//   grid-stride over 16-row tiles independently:
//     dense A-frags (4 global loads) ; gather edges (4 loads/edge) ;
//     64 MFMA (K=256: dense@Wr + agg@Wl, B via swizzled ds_read_b128) ;
//     bn/relu (folded: x=fma(acc,sc,bl*sc+sh), hoisted) ; scalar stores.
// LDS 64KB -> 2 blocks/CU (16 autonomous waves). launch_bounds(512,4).
// M%16==0 for both dirs (400000,100000) -> no bounds guards needed.
// ---------------------------------------------------------------------------

#define NUv   100000
#define NTv   400000
#define Ev    400000
#define Hv    128
#define NLv   3
#define HID2v 64
#define EPSv  1e-5f

typedef _Float16 h16;
typedef __attribute__((ext_vector_type(8))) _Float16 f16x8;
typedef __attribute__((ext_vector_type(4))) float    f32x4;

#define WS_NEED (280u * 1024u * 1024u)
__device__ __attribute__((aligned(256))) static unsigned char g_ws[WS_NEED];

__device__ __forceinline__ int imin(int a, int b) { return a < b ? a : b; }
// swizzled byte offset, 256B rows (sW in mlp)
__device__ __forceinline__ int swz(int n, int kbyte) {
  return n * 256 + (kbyte ^ ((n & 7) << 4));
}
// swizzled byte offset, 512B rows (sB: [Wr 256B | Wl 256B] per n)
__device__ __forceinline__ int swzB(int n, int kbyte) {
  return n * 512 + (kbyte ^ ((n & 7) << 4));
}

// ---------------------------------------------------------------- CSR build
__global__ __launch_bounds__(256) void k_count(const int* __restrict__ d0,
                                               const int* __restrict__ d1,
                                               int* __restrict__ c0,
                                               int* __restrict__ c1, int e) {
  int t = blockIdx.x * 256 + threadIdx.x;
  if (t < e) {
    atomicAdd(c0 + d0[t], 1);
    atomicAdd(c1 + d1[t], 1);
  }
}

// both directions in one launch: blocks [0,g0) -> cnt0, [g0,g0+g1) -> cnt1
__global__ __launch_bounds__(256) void k_blocksum2(const int* __restrict__ c0,
                                                   int n0, int g0,
                                                   const int* __restrict__ c1,
                                                   int n1,
                                                   int* __restrict__ bs0,
                                                   int* __restrict__ bs1) {
  __shared__ int red[256];
  int second = blockIdx.x >= g0 ? 1 : 0;
  const int* cnt = second ? c1 : c0;
  int n = second ? n1 : n0;
  int* bs = second ? bs1 : bs0;
  int bid = blockIdx.x - (second ? g0 : 0);
  int base = bid * 2048 + threadIdx.x * 8;
  int s = 0;
#pragma unroll
  for (int j = 0; j < 8; j++) {
    int p = base + j;
    if (p < n) s += cnt[p];
  }
  red[threadIdx.x] = s;
  __syncthreads();
  for (int st = 128; st > 0; st >>= 1) {
    if (threadIdx.x < st) red[threadIdx.x] += red[threadIdx.x + st];
    __syncthreads();
  }
  if (threadIdx.x == 0) bs[bid] = red[0];
}

// grid=2: block 0 scans bs0[g0], block 1 scans bs1[g1]
__global__ __launch_bounds__(256) void k_scansmall2(int* __restrict__ bs0, int g0,
                                                    int* __restrict__ bs1, int g1) {
  __shared__ int lds[256];
  int* bs = blockIdx.x ? bs1 : bs0;
  int g = blockIdx.x ? g1 : g0;
  int t = threadIdx.x;
  int v = (t < g) ? bs[t] : 0;
  lds[t] = v;
  __syncthreads();
  for (int st = 1; st < 256; st <<= 1) {
    int x = (t >= st) ? lds[t - st] : 0;
    __syncthreads();
    lds[t] += x;
    __syncthreads();
  }
  if (t < g) bs[t] = lds[t] - v;  // exclusive
}

__global__ __launch_bounds__(256) void k_scanfinal2(const int* __restrict__ c0,
                                                    int n0, int g0,
                                                    const int* __restrict__ bs0,
                                                    int* __restrict__ off0,
                                                    int* __restrict__ cur0,
                                                    const int* __restrict__ c1,
                                                    int n1,
                                                    const int* __restrict__ bs1,
                                                    int* __restrict__ off1,
                                                    int* __restrict__ cur1) {
  __shared__ int lds[256];
  int second = blockIdx.x >= g0 ? 1 : 0;
  const int* cnt = second ? c1 : c0;
  const int* bs = second ? bs1 : bs0;
  int* off = second ? off1 : off0;
  int* cur = second ? cur1 : cur0;
  int n = second ? n1 : n0;
  int bid = blockIdx.x - (second ? g0 : 0);
  int t = threadIdx.x;
  int base = bid * 2048 + t * 8;
  int v[8], pre[8];
  int tsum = 0;
#pragma unroll
  for (int j = 0; j < 8; j++) {
    int p = base + j;
    v[j] = (p < n) ? cnt[p] : 0;
    pre[j] = tsum;
    tsum += v[j];
  }
  lds[t] = tsum;
  __syncthreads();
  for (int st = 1; st < 256; st <<= 1) {
    int x = (t >= st) ? lds[t - st] : 0;
    __syncthreads();
    lds[t] += x;
    __syncthreads();
  }
  int texcl = lds[t] - tsum;
  int boff = bs[bid];
#pragma unroll
  for (int j = 0; j < 8; j++) {
    int p = base + j;
    if (p < n) {
      int o = boff + texcl + pre[j];
      off[p] = o;
      cur[p] = o;
      if (p == n - 1) off[n] = o + v[j];
    }
  }
}

__global__ __launch_bounds__(256) void k_fill(const int* __restrict__ s0,
                                              const int* __restrict__ d0,
                                              const int* __restrict__ s1,
                                              const int* __restrict__ d1,
                                              int* __restrict__ cur0,
                                              int* __restrict__ cur1,
                                              int* __restrict__ ss0,
                                              int* __restrict__ ss1, int e) {
  int t = blockIdx.x * 256 + threadIdx.x;
  if (t < e) {
    int p = atomicAdd(cur0 + d0[t], 1);
    ss0[p] = s0[t];
    int q = atomicAdd(cur1 + d1[t], 1);
    ss1[q] = s1[t];
  }
}

// -------------------------------------------- weight transpose + bn prep
__global__ __launch_bounds__(256) void k_wtbn(const float* __restrict__ Wl,
                                              const float* __restrict__ Wr,
                                              const float* __restrict__ W1,
                                              const float* __restrict__ g,
                                              const float* __restrict__ b,
                                              const float* __restrict__ m,
                                              const float* __restrict__ v,
                                              h16* __restrict__ WlT,
                                              h16* __restrict__ WrT,
                                              h16* __restrict__ W1T,
                                              float* __restrict__ sc,
                                              float* __restrict__ sh) {
  int t = blockIdx.x * 256 + threadIdx.x;
  const int NW = NLv * 2 * Hv * Hv;  // 196608
  const int NW1 = NW + HID2v * Hv;   // +8192
  if (t < NW) {
    int mat = t / (Hv * Hv);
    int n = (t / Hv) % Hv;
    int k = t % Hv;
    WlT[t] = (h16)Wl[(size_t)mat * Hv * Hv + (size_t)k * Hv + n];
    WrT[t] = (h16)Wr[(size_t)mat * Hv * Hv + (size_t)k * Hv + n];
  } else if (t < NW1) {
    int u = t - NW;
    int n = u / Hv;
    int k = u % Hv;
    W1T[u] = (h16)W1[(size_t)k * HID2v + n];
  } else if (t < NW1 + NLv * 2 * Hv) {
    int u = t - NW1;
    float inv = rsqrtf(v[u] + EPSv);
    float s = g[u] * inv;
    sc[u] = s;
    sh[u] = b[u] - m[u] * s;
  }
}

// ------------------------------------------------------------- embeddings
__global__ __launch_bounds__(256) void k_embed(const int* __restrict__ xu,
                                               const int* __restrict__ xt,
                                               const float* __restrict__ eu,
                                               const float* __restrict__ et,
                                               h16* __restrict__ hu,
                                               h16* __restrict__ ht) {
  int t = blockIdx.x * 256 + threadIdx.x;
  int row = t >> 4;
  int c = (t & 15) * 8;
  if (row >= NUv + NTv) return;
  const float* src;
  h16* dst;
  if (row < NUv) {
    src = eu + (size_t)xu[row] * Hv;
    dst = hu + (size_t)row * Hv;
  } else {
    int r2 = row - NUv;
    src = et + (size_t)xt[r2] * Hv;
    dst = ht + (size_t)r2 * Hv;
  }
  float4 v0 = *(const float4*)(src + c);
  float4 v1 = *(const float4*)(src + c + 4);
  f16x8 o;
  o[0] = (h16)v0.x; o[1] = (h16)v0.y; o[2] = (h16)v0.z; o[3] = (h16)v0.w;
  o[4] = (h16)v1.x; o[5] = (h16)v1.y; o[6] = (h16)v1.z; o[7] = (h16)v1.w;
  *(f16x8*)(dst + c) = o;
}

// ------------------------- wave-autonomous fused gather+GEMM+bn (no bars)
// OUT = relu(bn(seg_mean(SRC via off/ss) @ BTl + DENSE @ BTr + bl))
// mfma_f32_16x16x32_f16 (learn_hip m89):
//   A frag: a[j]=A[lane&15][kblk*32+(lane>>4)*8+j]
//   B frag: b[j]=B[kblk*32+(lane>>4)*8+j][lane&15]  (B^T stored [N][K])
//   D frag: d[r]=D[(lane>>4)*4+r][lane&15]
// Each wave owns a 16-row tile; lane l gathers row base+(l&15) cols
// (l>>4)*8+{0..7}+{0,32,64,96} into facc[32] == its A-fragment set.
// REQUIRES M % 16 == 0 (no row guards) and DENSE != C (no store ordering).
__global__ __launch_bounds__(512, 4) void k_fused(const h16* __restrict__ SRC,
                                                  const h16* __restrict__ DENSE,
                                                  const int* __restrict__ off,
                                                  const int* __restrict__ ss,
                                                  const h16* __restrict__ BTl,
                                                  const h16* __restrict__ BTr,
                                                  const float* __restrict__ bl,
                                                  const float* __restrict__ sc,
                                                  const float* __restrict__ sh,
                                                  h16* __restrict__ C, int M) {
  __shared__ __align__(16) unsigned char sB[128 * 512];  // 64 KB [Wr|Wl]

  int t = threadIdx.x;
  int l = t & 63, lm = l & 15, lk = l >> 4;
  int w = t >> 6;

  // ---- stage sB = [BTr | BTl] once, swizzled
  {
    int n = t >> 2;
    int kb = (t & 3) * 64;
    const h16* sr = BTr + t * 32;
    f16x8 r0 = *(const f16x8*)(sr + 0);
    f16x8 r1 = *(const f16x8*)(sr + 8);
    f16x8 r2 = *(const f16x8*)(sr + 16);
    f16x8 r3 = *(const f16x8*)(sr + 24);
    const h16* sl = BTl + t * 32;
    f16x8 l0 = *(const f16x8*)(sl + 0);
    f16x8 l1 = *(const f16x8*)(sl + 8);
    f16x8 l2 = *(const f16x8*)(sl + 16);
    f16x8 l3 = *(const f16x8*)(sl + 24);
    *(f16x8*)(sB + swzB(n, kb + 0)) = r0;
    *(f16x8*)(sB + swzB(n, kb + 16)) = r1;
    *(f16x8*)(sB + swzB(n, kb + 32)) = r2;
    *(f16x8*)(sB + swzB(n, kb + 48)) = r3;
    *(f16x8*)(sB + swzB(n, 256 + kb + 0)) = l0;
    *(f16x8*)(sB + swzB(n, 256 + kb + 16)) = l1;
    *(f16x8*)(sB + swzB(n, 256 + kb + 32)) = l2;
    *(f16x8*)(sB + swzB(n, 256 + kb + 48)) = l3;
  }

  // ---- hoist folded bn params: x = fma(acc, scv, bl*sc+sh)
  float scv[8], shv[8];
#pragma unroll
  for (int j = 0; j < 8; j++) {
    int col = j * 16 + lm;
    float s = sc[col];
    scv[j] = s;
    shv[j] = fmaf(bl[col], s, sh[col]);
  }
  __syncthreads();  // the only barrier

  int nWT = M >> 4;  // 16-row wave tiles
  for (int wt = blockIdx.x * 8 + w; wt < nWT; wt += gridDim.x * 8) {
    int base = wt << 4;
    int rowA = base + lm;

    // dense A-frags (issued first; latency overlaps gather)
    const h16* arow = DENSE + (size_t)rowA * Hv + lk * 8;
    f16x8 ad0 = *(const f16x8*)(arow);
    f16x8 ad1 = *(const f16x8*)(arow + 32);
    f16x8 ad2 = *(const f16x8*)(arow + 64);
    f16x8 ad3 = *(const f16x8*)(arow + 96);

    // gather seg_mean into registers (per-lane: its own A-frag cols)
    float facc[32];
#pragma unroll
    for (int j = 0; j < 32; j++) facc[j] = 0.f;
    int e0 = off[rowA], e1 = off[rowA + 1];
    for (int e = e0; e < e1; ++e) {
      const h16* sp = SRC + (size_t)ss[e] * Hv + lk * 8;
      f16x8 v0 = *(const f16x8*)(sp);
      f16x8 v1 = *(const f16x8*)(sp + 32);
      f16x8 v2 = *(const f16x8*)(sp + 64);
      f16x8 v3 = *(const f16x8*)(sp + 96);
#pragma unroll
      for (int j = 0; j < 8; j++) {
        facc[j] += (float)v0[j];
        facc[8 + j] += (float)v1[j];
        facc[16 + j] += (float)v2[j];
        facc[24 + j] += (float)v3[j];
      }
    }
    {
      int deg = e1 - e0;
      float inv = 1.f / (float)(deg > 1 ? deg : 1);
#pragma unroll
      for (int j = 0; j < 32; j++) facc[j] *= inv;
    }
    f16x8 aA0, aA1, aA2, aA3;
#pragma unroll
    for (int j = 0; j < 8; j++) {
      aA0[j] = (h16)facc[j];
      aA1[j] = (h16)facc[8 + j];
      aA2[j] = (h16)facc[16 + j];
      aA3[j] = (h16)facc[24 + j];
    }

    // K=256 MFMA: dense @ Wr + agg @ Wl (B via swizzled ds_read_b128)
    f32x4 acc[8];
#pragma unroll
    for (int j = 0; j < 8; j++) acc[j] = (f32x4){0.f, 0.f, 0.f, 0.f};
    {
      f16x8 ads[4] = {ad0, ad1, ad2, ad3};
      f16x8 aAs[4] = {aA0, aA1, aA2, aA3};
#pragma unroll
      for (int s = 0; s < 4; s++) {
#pragma unroll
        for (int j = 0; j < 8; j++) {
          int n = j * 16 + lm;
          f16x8 br = *(const f16x8*)(sB + swzB(n, s * 64 + lk * 16));
          acc[j] = __builtin_amdgcn_mfma_f32_16x16x32_f16(ads[s], br, acc[j], 0, 0, 0);
          f16x8 bw = *(const f16x8*)(sB + swzB(n, 256 + s * 64 + lk * 16));
          acc[j] = __builtin_amdgcn_mfma_f32_16x16x32_f16(aAs[s], bw, acc[j], 0, 0, 0);
        }
      }
    }

    // epilogue: folded bn + relu, direct stores (no write-amp per r8)
#pragma unroll
    for (int j = 0; j < 8; j++) {
      int col = j * 16 + lm;
#pragma unroll
      for (int r_ = 0; r_ < 4; r_++) {
        int row = base + lk * 4 + r_;
        float x = fmaf(acc[j][r_], scv[j], shv[j]);
        C[(size_t)row * Hv + col] = (h16)fmaxf(x, 0.f);
      }
    }
  }
}

// out = relu(h @ W1 + b1) @ W2 + b2, h = [h_u ; h_t] virtual concat
__global__ __launch_bounds__(512, 4) void k_mlp(const h16* __restrict__ HU,
                                                const h16* __restrict__ HT,
                                                const h16* __restrict__ W1T,
                                                const float* __restrict__ b1,
                                                const float* __restrict__ W2,
                                                const float* __restrict__ b2,
                                                float* __restrict__ out, int Mtot) {
  __shared__ float y[128][65];                       // 33280 B
  __shared__ __align__(16) unsigned char sW[64 * 256];  // 16 KB, swizzled
  int t = threadIdx.x;
  int w = t >> 6, l = t & 63;
  int lm = l & 15, lk = l >> 4;

  // stage W1T (8192 h16) coalesced: thread t owns 16 h16
  {
    const h16* src = W1T + t * 16;
    f16x8 w0 = *(const f16x8*)(src + 0);
    f16x8 w1 = *(const f16x8*)(src + 8);
    int n = (t * 16) >> 7;
    int kb = ((t * 16) & 127) * 2;
    *(f16x8*)(sW + swz(n, kb + 0)) = w0;
    *(f16x8*)(sW + swz(n, kb + 16)) = w1;
  }

  int rowBase = blockIdx.x * 128 + w * 16;
  int ar = imin(rowBase + lm, Mtot - 1);
  const h16* arow =
      (ar < NUv) ? (HU + (size_t)ar * Hv) : (HT + (size_t)(ar - NUv) * Hv);
  f16x8 a0 = *(const f16x8*)(arow + 0 * 32 + lk * 8);
  f16x8 a1 = *(const f16x8*)(arow + 1 * 32 + lk * 8);
  f16x8 a2 = *(const f16x8*)(arow + 2 * 32 + lk * 8);
  f16x8 a3 = *(const f16x8*)(arow + 3 * 32 + lk * 8);
  __syncthreads();

  f32x4 acc[4];
#pragma unroll
  for (int nf = 0; nf < 4; nf++) acc[nf] = (f32x4){0.f, 0.f, 0.f, 0.f};
  {
    f16x8 as[4] = {a0, a1, a2, a3};
#pragma unroll
    for (int s = 0; s < 4; s++) {
#pragma unroll
      for (int nf = 0; nf < 4; nf++) {
        f16x8 b = *(const f16x8*)(sW + swz(nf * 16 + lm, s * 64 + lk * 16));
        acc[nf] = __builtin_amdgcn_mfma_f32_16x16x32_f16(as[s], b, acc[nf], 0, 0, 0);
      }
    }
  }
#pragma unroll
  for (int nf = 0; nf < 4; nf++) {
    int col = nf * 16 + lm;
    float b1v = b1[col];
#pragma unroll
    for (int r = 0; r < 4; r++) {
      int rloc = w * 16 + lk * 4 + r;
      y[rloc][col] = fmaxf(acc[nf][r] + b1v, 0.f);
    }
  }
  __syncthreads();
  if (t < 256) {
    int rloc = t >> 1, o = t & 1;
    int row = blockIdx.x * 128 + rloc;
    if (row < Mtot) {
      float sum = b2[o];
#pragma unroll
      for (int k = 0; k < HID2v; k++) sum += y[rloc][k] * W2[k * 2 + o];
      out[(size_t)row * 2 + o] = sum;
    }
  }
}

// ---------------------------------------------------------------- launcher
extern "C" void kernel_launch(void* const* d_in, const int* in_sizes, int n_in,
                              void* d_out, int out_size, void* d_ws, size_t ws_size,
                              hipStream_t stream) {
  (void)in_sizes; (void)n_in; (void)out_size;

  const int* x_user  = (const int*)d_in[0];
  const int* x_txn   = (const int*)d_in[1];
  const int* ei0_src = (const int*)d_in[2];
  const int* ei0_dst = (const int*)d_in[3];
  const int* ei1_src = (const int*)d_in[4];
  const int* ei1_dst = (const int*)d_in[5];
  const float* emb_user = (const float*)d_in[6];
  const float* emb_txn  = (const float*)d_in[7];
  const float* Wl = (const float*)d_in[8];
  const float* bl = (const float*)d_in[9];
  const float* Wr = (const float*)d_in[10];
  const float* bn_g = (const float*)d_in[11];
  const float* bn_b = (const float*)d_in[12];
  const float* bn_m = (const float*)d_in[13];
  const float* bn_v = (const float*)d_in[14];
  const float* W1 = (const float*)d_in[15];
  const float* b1 = (const float*)d_in[16];
  const float* W2 = (const float*)d_in[17];
  const float* b2 = (const float*)d_in[18];
  float* out = (float*)d_out;

  char* wsb;
  if (ws_size >= (size_t)WS_NEED) {
    wsb = (char*)d_ws;
  } else {
    void* sym = nullptr;
    hipGetSymbolAddress(&sym, HIP_SYMBOL(g_ws));
    wsb = (char*)sym;
  }
  size_t o = 0;
  auto alloc = [&](size_t bytes) -> void* {
    o = (o + 255) & ~(size_t)255;
    void* p = wsb + o;
    o += bytes;
    return p;
  };
  h16* hu0  = (h16*)alloc((size_t)NUv * Hv * 2);   // ping-pong
  h16* hu1  = (h16*)alloc((size_t)NUv * Hv * 2);
  h16* ht0  = (h16*)alloc((size_t)NTv * Hv * 2);   // ping-pong
  h16* ht1  = (h16*)alloc((size_t)NTv * Hv * 2);
  h16* WlT  = (h16*)alloc((size_t)NLv * 2 * Hv * Hv * 2);
  h16* WrT  = (h16*)alloc((size_t)NLv * 2 * Hv * Hv * 2);
  h16* W1T  = (h16*)alloc((size_t)HID2v * Hv * 2);
  float* bnsc = (float*)alloc((size_t)NLv * 2 * Hv * 4);
  float* bnsh = (float*)alloc((size_t)NLv * 2 * Hv * 4);
  int* off0 = (int*)alloc((size_t)(NTv + 1) * 4);
  int* off1 = (int*)alloc((size_t)(NUv + 1) * 4);
  int* cur0 = (int*)alloc((size_t)NTv * 4);
  int* cur1 = (int*)alloc((size_t)NUv * 4);
  int* ss0  = (int*)alloc((size_t)Ev * 4);
  int* ss1  = (int*)alloc((size_t)Ev * 4);
  int* bs0  = (int*)alloc(256 * 4);
  int* bs1  = (int*)alloc(256 * 4);

  const int G_E    = (Ev + 255) / 256;
  const int G_BS0  = (NTv + 2047) / 2048;        // 196
  const int G_BS1  = (NUv + 2047) / 2048;        // 49
  const int G_EMB  = ((NUv + NTv) * 16 + 255) / 256;
  const int N_WTBN = NLv * 2 * Hv * Hv + HID2v * Hv + NLv * 2 * Hv;
  const int G_WTBN = (N_WTBN + 255) / 256;
  const int G_F    = 512;                        // persistent grid
  const int G_MLP  = (NUv + NTv + 127) / 128;    // 3907

  // 1. CSR build (paired kernels handle both directions per launch)
  hipMemsetAsync(cur0, 0, (size_t)NTv * 4, stream);
  hipMemsetAsync(cur1, 0, (size_t)NUv * 4, stream);
  k_count<<<G_E, 256, 0, stream>>>(ei0_dst, ei1_dst, cur0, cur1, Ev);
  k_blocksum2<<<G_BS0 + G_BS1, 256, 0, stream>>>(cur0, NTv, G_BS0, cur1, NUv,
                                                 bs0, bs1);
  k_scansmall2<<<2, 256, 0, stream>>>(bs0, G_BS0, bs1, G_BS1);
  k_scanfinal2<<<G_BS0 + G_BS1, 256, 0, stream>>>(cur0, NTv, G_BS0, bs0, off0,
                                                  cur0, cur1, NUv, bs1, off1,
                                                  cur1);
  k_fill<<<G_E, 256, 0, stream>>>(ei0_src, ei0_dst, ei1_src, ei1_dst,
                                  cur0, cur1, ss0, ss1, Ev);

  // 2. weight conversion + bn prep (one launch)
  k_wtbn<<<G_WTBN, 256, 0, stream>>>(Wl, Wr, W1, bn_g, bn_b, bn_m, bn_v,
                                     WlT, WrT, W1T, bnsc, bnsh);

  // 3. embedding gather
  k_embed<<<G_EMB, 256, 0, stream>>>(x_user, x_txn, emb_user, emb_txn, hu0, ht0);

  // 4. layers (separate T/U dispatches; wave-autonomous kernel)
  h16* hu_cur = hu0; h16* hu_nxt = hu1;
  h16* ht_cur = ht0; h16* ht_nxt = ht1;
  for (int i = 0; i < NLv; i++) {
    const h16* WlT0 = WlT + (size_t)(i * 2 + 0) * Hv * Hv;
    const h16* WlT1 = WlT + (size_t)(i * 2 + 1) * Hv * Hv;
    const h16* WrT0 = WrT + (size_t)(i * 2 + 0) * Hv * Hv;
    const h16* WrT1 = WrT + (size_t)(i * 2 + 1) * Hv * Hv;
    const float* bl0 = bl + (size_t)(i * 2 + 0) * Hv;
    const float* bl1 = bl + (size_t)(i * 2 + 1) * Hv;
    const float* sc0 = bnsc + (size_t)(i * 2 + 0) * Hv;
    const float* sh0 = bnsh + (size_t)(i * 2 + 0) * Hv;
    const float* sc1 = bnsc + (size_t)(i * 2 + 1) * Hv;
    const float* sh1 = bnsh + (size_t)(i * 2 + 1) * Hv;

    // h_t' : agg CSR0 (src=hu_cur), dense=ht_cur -> ht_nxt ; bn[i,1]
    k_fused<<<G_F, 512, 0, stream>>>(hu_cur, ht_cur, off0, ss0, WlT0, WrT0,
                                     bl0, sc1, sh1, ht_nxt, NTv);
    // h_u' : agg CSR1 (src=ht_cur OLD), dense=hu_cur -> hu_nxt ; bn[i,0]
    k_fused<<<G_F, 512, 0, stream>>>(ht_cur, hu_cur, off1, ss1, WlT1, WrT1,
                                     bl1, sc0, sh0, hu_nxt, NUv);
    h16* tmp;
    tmp = ht_cur; ht_cur = ht_nxt; ht_nxt = tmp;
    tmp = hu_cur; hu_cur = hu_nxt; hu_nxt = tmp;
  }

  // 5. MLP head
  k_mlp<<<G_MLP, 512, 0, stream>>>(hu_cur, ht_cur, W1T, b1, W2, b2, out,
                                   NUv + NTv);
}

// Round 13
// 654.029 us; speedup vs baseline: 3.0605x; 3.0605x over previous
//
#include <hip/hip_runtime.h>

// ---------------------------------------------------------------------------
// HeteroFraudGNN on MI355X — round 13: r8 body (best measured: 660us, T=94us,
// VGPR=56) + degree-sorted row permutation to kill the gather straggler.
// r12 lesson (3rd occurrence): designs needing >~60 live VGPRs spill and die.
// New: counting-sort rows by CSR degree (32 bins) -> perm[]; each 64-row tile
// then has uniform degree, so the per-tile barrier no longer waits on a
// max-degree straggler. Kernel indexes rows via perm (gather/dense/store);
// tile-local sA/MFMA/barrier structure is exactly r8's.
// ---------------------------------------------------------------------------

#define NUv   100000
#define NTv   400000
#define Ev    400000
#define Hv    128
#define NLv   3
#define HID2v 64
#define EPSv  1e-5f

typedef _Float16 h16;
typedef __attribute__((ext_vector_type(8))) _Float16 f16x8;
typedef __attribute__((ext_vector_type(4))) float    f32x4;

#define WS_NEED (280u * 1024u * 1024u)
__device__ __attribute__((aligned(256))) static unsigned char g_ws[WS_NEED];

__device__ __forceinline__ int imin(int a, int b) { return a < b ? a : b; }
// swizzled byte offset, 256B rows (sA)
__device__ __forceinline__ int swz(int n, int kbyte) {
  return n * 256 + (kbyte ^ ((n & 7) << 4));
}
// swizzled byte offset, 512B rows (sB: [Wr 256B | Wl 256B] per n)
__device__ __forceinline__ int swzB(int n, int kbyte) {
  return n * 512 + (kbyte ^ ((n & 7) << 4));
}

// ---------------------------------------------------------------- CSR build
__global__ __launch_bounds__(256) void k_count(const int* __restrict__ d0,
                                               const int* __restrict__ d1,
                                               int* __restrict__ c0,
                                               int* __restrict__ c1, int e) {
  int t = blockIdx.x * 256 + threadIdx.x;
  if (t < e) {
    atomicAdd(c0 + d0[t], 1);
    atomicAdd(c1 + d1[t], 1);
  }
}

__global__ __launch_bounds__(256) void k_blocksum2(const int* __restrict__ c0,
                                                   int n0, int g0,
                                                   const int* __restrict__ c1,
                                                   int n1,
                                                   int* __restrict__ bs0,
                                                   int* __restrict__ bs1) {
  __shared__ int red[256];
  int second = blockIdx.x >= g0 ? 1 : 0;
  const int* cnt = second ? c1 : c0;
  int n = second ? n1 : n0;
  int* bs = second ? bs1 : bs0;
  int bid = blockIdx.x - (second ? g0 : 0);
  int base = bid * 2048 + threadIdx.x * 8;
  int s = 0;
#pragma unroll
  for (int j = 0; j < 8; j++) {
    int p = base + j;
    if (p < n) s += cnt[p];
  }
  red[threadIdx.x] = s;
  __syncthreads();
  for (int st = 128; st > 0; st >>= 1) {
    if (threadIdx.x < st) red[threadIdx.x] += red[threadIdx.x + st];
    __syncthreads();
  }
  if (threadIdx.x == 0) bs[bid] = red[0];
}

__global__ __launch_bounds__(256) void k_scansmall2(int* __restrict__ bs0, int g0,
                                                    int* __restrict__ bs1, int g1) {
  __shared__ int lds[256];
  int* bs = blockIdx.x ? bs1 : bs0;
  int g = blockIdx.x ? g1 : g0;
  int t = threadIdx.x;
  int v = (t < g) ? bs[t] : 0;
  lds[t] = v;
  __syncthreads();
  for (int st = 1; st < 256; st <<= 1) {
    int x = (t >= st) ? lds[t - st] : 0;
    __syncthreads();
    lds[t] += x;
    __syncthreads();
  }
  if (t < g) bs[t] = lds[t] - v;  // exclusive
}

__global__ __launch_bounds__(256) void k_scanfinal2(const int* __restrict__ c0,
                                                    int n0, int g0,
                                                    const int* __restrict__ bs0,
                                                    int* __restrict__ off0,
                                                    int* __restrict__ cur0,
                                                    const int* __restrict__ c1,
                                                    int n1,
                                                    const int* __restrict__ bs1,
                                                    int* __restrict__ off1,
                                                    int* __restrict__ cur1) {
  __shared__ int lds[256];
  int second = blockIdx.x >= g0 ? 1 : 0;
  const int* cnt = second ? c1 : c0;
  const int* bs = second ? bs1 : bs0;
  int* off = second ? off1 : off0;
  int* cur = second ? cur1 : cur0;
  int n = second ? n1 : n0;
  int bid = blockIdx.x - (second ? g0 : 0);
  int t = threadIdx.x;
  int base = bid * 2048 + t * 8;
  int v[8], pre[8];
  int tsum = 0;
#pragma unroll
  for (int j = 0; j < 8; j++) {
    int p = base + j;
    v[j] = (p < n) ? cnt[p] : 0;
    pre[j] = tsum;
    tsum += v[j];
  }
  lds[t] = tsum;
  __syncthreads();
  for (int st = 1; st < 256; st <<= 1) {
    int x = (t >= st) ? lds[t - st] : 0;
    __syncthreads();
    lds[t] += x;
    __syncthreads();
  }
  int texcl = lds[t] - tsum;
  int boff = bs[bid];
#pragma unroll
  for (int j = 0; j < 8; j++) {
    int p = base + j;
    if (p < n) {
      int o = boff + texcl + pre[j];
      off[p] = o;
      cur[p] = o;
      if (p == n - 1) off[n] = o + v[j];
    }
  }
}

__global__ __launch_bounds__(256) void k_fill(const int* __restrict__ s0,
                                              const int* __restrict__ d0,
                                              const int* __restrict__ s1,
                                              const int* __restrict__ d1,
                                              int* __restrict__ cur0,
                                              int* __restrict__ cur1,
                                              int* __restrict__ ss0,
                                              int* __restrict__ ss1, int e) {
  int t = blockIdx.x * 256 + threadIdx.x;
  if (t < e) {
    int p = atomicAdd(cur0 + d0[t], 1);
    ss0[p] = s0[t];
    int q = atomicAdd(cur1 + d1[t], 1);
    ss1[q] = s1[t];
  }
}

// ------------------------------------------------ degree sort (counting)
__global__ __launch_bounds__(256) void k_deghist2(const int* __restrict__ off0,
                                                  int n0, int g0,
                                                  const int* __restrict__ off1,
                                                  int n1,
                                                  int* __restrict__ h0,
                                                  int* __restrict__ h1) {
  __shared__ int lh[32];
  int t = threadIdx.x;
  if (t < 32) lh[t] = 0;
  __syncthreads();
  int second = blockIdx.x >= g0 ? 1 : 0;
  const int* off = second ? off1 : off0;
  int n = second ? n1 : n0;
  int* h = second ? h1 : h0;
  int r = (blockIdx.x - (second ? g0 : 0)) * 256 + t;
  if (r < n) {
    int d = off[r + 1] - off[r];
    if (d > 31) d = 31;
    atomicAdd(&lh[d], 1);
  }
  __syncthreads();
  if (t < 32 && lh[t]) atomicAdd(&h[t], lh[t]);
}

__global__ __launch_bounds__(64) void k_degscan2(int* __restrict__ h0,
                                                 int* __restrict__ h1) {
  int* h = blockIdx.x ? h1 : h0;
  if (threadIdx.x == 0) {
    int s = 0;
    for (int i = 0; i < 32; i++) {
      int v = h[i];
      h[i] = s;
      s += v;
    }
  }
}

__global__ __launch_bounds__(256) void k_degscatter2(const int* __restrict__ off0,
                                                     int n0, int g0,
                                                     const int* __restrict__ off1,
                                                     int n1,
                                                     int* __restrict__ cur0,
                                                     int* __restrict__ cur1,
                                                     int* __restrict__ p0,
                                                     int* __restrict__ p1) {
  __shared__ int lh[32], lstart[32];
  int t = threadIdx.x;
  if (t < 32) lh[t] = 0;
  __syncthreads();
  int second = blockIdx.x >= g0 ? 1 : 0;
  const int* off = second ? off1 : off0;
  int n = second ? n1 : n0;
  int* cur = second ? cur1 : cur0;
  int* perm = second ? p1 : p0;
  int r = (blockIdx.x - (second ? g0 : 0)) * 256 + t;
  int bin = 0;
  if (r < n) {
    int d = off[r + 1] - off[r];
    bin = d > 31 ? 31 : d;
    atomicAdd(&lh[bin], 1);
  }
  __syncthreads();
  if (t < 32) {
    if (lh[t]) lstart[t] = atomicAdd(&cur[t], lh[t]);
    lh[t] = 0;
  }
  __syncthreads();
  if (r < n) {
    int rank = atomicAdd(&lh[bin], 1);
    perm[lstart[bin] + rank] = r;
  }
}

// -------------------------------------------- weight transpose + bn prep
__global__ __launch_bounds__(256) void k_wtbn(const float* __restrict__ Wl,
                                              const float* __restrict__ Wr,
                                              const float* __restrict__ W1,
                                              const float* __restrict__ g,
                                              const float* __restrict__ b,
                                              const float* __restrict__ m,
                                              const float* __restrict__ v,
                                              h16* __restrict__ WlT,
                                              h16* __restrict__ WrT,
                                              h16* __restrict__ W1T,
                                              float* __restrict__ sc,
                                              float* __restrict__ sh) {
  int t = blockIdx.x * 256 + threadIdx.x;
  const int NW = NLv * 2 * Hv * Hv;  // 196608
  const int NW1 = NW + HID2v * Hv;   // +8192
  if (t < NW) {
    int mat = t / (Hv * Hv);
    int n = (t / Hv) % Hv;
    int k = t % Hv;
    WlT[t] = (h16)Wl[(size_t)mat * Hv * Hv + (size_t)k * Hv + n];
    WrT[t] = (h16)Wr[(size_t)mat * Hv * Hv + (size_t)k * Hv + n];
  } else if (t < NW1) {
    int u = t - NW;
    int n = u / Hv;
    int k = u % Hv;
    W1T[u] = (h16)W1[(size_t)k * HID2v + n];
  } else if (t < NW1 + NLv * 2 * Hv) {
    int u = t - NW1;
    float inv = rsqrtf(v[u] + EPSv);
    float s = g[u] * inv;
    sc[u] = s;
    sh[u] = b[u] - m[u] * s;
  }
}

// ------------------------------------------------------------- embeddings
__global__ __launch_bounds__(256) void k_embed(const int* __restrict__ xu,
                                               const int* __restrict__ xt,
                                               const float* __restrict__ eu,
                                               const float* __restrict__ et,
                                               h16* __restrict__ hu,
                                               h16* __restrict__ ht) {
  int t = blockIdx.x * 256 + threadIdx.x;
  int row = t >> 4;
  int c = (t & 15) * 8;
  if (row >= NUv + NTv) return;
  const float* src;
  h16* dst;
  if (row < NUv) {
    src = eu + (size_t)xu[row] * Hv;
    dst = hu + (size_t)row * Hv;
  } else {
    int r2 = row - NUv;
    src = et + (size_t)xt[r2] * Hv;
    dst = ht + (size_t)r2 * Hv;
  }
  float4 v0 = *(const float4*)(src + c);
  float4 v1 = *(const float4*)(src + c + 4);
  f16x8 o;
  o[0] = (h16)v0.x; o[1] = (h16)v0.y; o[2] = (h16)v0.z; o[3] = (h16)v0.w;
  o[4] = (h16)v1.x; o[5] = (h16)v1.y; o[6] = (h16)v1.z; o[7] = (h16)v1.w;
  *(f16x8*)(dst + c) = o;
}

// --------------------------------------------------- fused gather+GEMM+bn
// OUT[perm[p]] = relu(bn(seg_mean(SRC via off/ss over perm[p]) @ BTl
//                        + DENSE[perm[p]] @ BTr + bl))
// r8's verified 2-barrier body; rows indexed through degree-sorted perm so
// each 64-row tile has uniform degree (no gather straggler at the barrier).
// mfma_f32_16x16x32_f16 (learn_hip m89):
//   A frag: a[j]=A[lane&15][kblk*32+(lane>>4)*8+j]
//   B frag: b[j]=B[kblk*32+(lane>>4)*8+j][lane&15]  (B^T stored [N][K])
//   D frag: d[r]=D[(lane>>4)*4+r][lane&15]
// 8 waves: rg=w>>1 (16-row group), cg=w&1 (64-col half).
__global__ __launch_bounds__(512, 4) void k_fused(const h16* __restrict__ SRC,
                                                  const h16* __restrict__ DENSE,
                                                  const int* __restrict__ off,
                                                  const int* __restrict__ ss,
                                                  const int* __restrict__ perm,
                                                  const h16* __restrict__ BTl,
                                                  const h16* __restrict__ BTr,
                                                  const float* __restrict__ bl,
                                                  const float* __restrict__ sc,
                                                  const float* __restrict__ sh,
                                                  h16* __restrict__ C, int M) {
  __shared__ __align__(16) unsigned char sB[128 * 512];  // 64 KB [Wr|Wl]
  __shared__ __align__(16) unsigned char sA[64 * 256];   // 16 KB gather tile

  int t = threadIdx.x;
  int l = t & 63;
  int lm = l & 15, lk = l >> 4;
  int w = t >> 6;
  int rg = w >> 1, cg = w & 1;

  // ---- stage sB ONCE: row n = [BTr_n (256B) | BTl_n (256B)], swizzled
  {
    int n = t >> 2;
    int kb = (t & 3) * 64;
    const h16* sr = BTr + t * 32;
    f16x8 r0 = *(const f16x8*)(sr + 0);
    f16x8 r1 = *(const f16x8*)(sr + 8);
    f16x8 r2 = *(const f16x8*)(sr + 16);
    f16x8 r3 = *(const f16x8*)(sr + 24);
    const h16* sl = BTl + t * 32;
    f16x8 l0 = *(const f16x8*)(sl + 0);
    f16x8 l1 = *(const f16x8*)(sl + 8);
    f16x8 l2 = *(const f16x8*)(sl + 16);
    f16x8 l3 = *(const f16x8*)(sl + 24);
    *(f16x8*)(sB + swzB(n, kb + 0)) = r0;
    *(f16x8*)(sB + swzB(n, kb + 16)) = r1;
    *(f16x8*)(sB + swzB(n, kb + 32)) = r2;
    *(f16x8*)(sB + swzB(n, kb + 48)) = r3;
    *(f16x8*)(sB + swzB(n, 256 + kb + 0)) = l0;
    *(f16x8*)(sB + swzB(n, 256 + kb + 16)) = l1;
    *(f16x8*)(sB + swzB(n, 256 + kb + 32)) = l2;
    *(f16x8*)(sB + swzB(n, 256 + kb + 48)) = l3;
  }

  // ---- hoist folded bn for this wave's 4 output col-frags:
  //      x = fma(acc, scv, bl*sc+sh)
  float scv[4], shv[4];
#pragma unroll
  for (int j = 0; j < 4; j++) {
    int col = (cg * 4 + j) * 16 + lm;
    float s = sc[col];
    scv[j] = s;
    shv[j] = fmaf(bl[col], s, sh[col]);
  }
  __syncthreads();

  int nTiles = (M + 63) / 64;
  for (int tile = blockIdx.x; tile < nTiles; tile += gridDim.x) {
    int base = tile * 64;

    // ---- dense A-frags for this tile's (permuted) rows, issued early
    int posD = imin(base + rg * 16 + lm, M - 1);
    int prowD = perm[posD];
    const h16* arow = DENSE + (size_t)prowD * Hv;
    f16x8 ad0 = *(const f16x8*)(arow + 0 * 32 + lk * 8);
    f16x8 ad1 = *(const f16x8*)(arow + 1 * 32 + lk * 8);
    f16x8 ad2 = *(const f16x8*)(arow + 2 * 32 + lk * 8);
    f16x8 ad3 = *(const f16x8*)(arow + 3 * 32 + lk * 8);

    // ---- gather seg_mean -> sA (8 thr/row, 16 h16 cols, 2-deep pipeline)
    {
      int r = t >> 3;
      int cs = (t & 7) * 16;
      float facc[16];
#pragma unroll
      for (int j = 0; j < 16; j++) facc[j] = 0.f;
      int pos = base + r;
      if (pos < M) {
        int prow = perm[pos];
        int e0 = off[prow], e1 = off[prow + 1];
        for (int e = e0; e < e1; e += 2) {
          int i0 = ss[e];
          bool v1 = (e + 1) < e1;
          int i1 = v1 ? ss[e + 1] : i0;
          const f16x8* p0 = (const f16x8*)(SRC + (size_t)i0 * Hv + cs);
          const f16x8* p1 = (const f16x8*)(SRC + (size_t)i1 * Hv + cs);
          f16x8 x0 = p0[0], x1 = p0[1];
          f16x8 y0 = p1[0], y1 = p1[1];
          float m1 = v1 ? 1.f : 0.f;
#pragma unroll
          for (int j = 0; j < 8; j++) {
            facc[j] += (float)x0[j];
            facc[8 + j] += (float)x1[j];
            facc[j] = fmaf((float)y0[j], m1, facc[j]);
            facc[8 + j] = fmaf((float)y1[j], m1, facc[8 + j]);
          }
        }
        int deg = e1 - e0;
        float inv = 1.f / (float)(deg > 1 ? deg : 1);
#pragma unroll
        for (int j = 0; j < 16; j++) facc[j] *= inv;
      }
#pragma unroll
      for (int q = 0; q < 2; q++) {
        f16x8 ov;
#pragma unroll
        for (int j = 0; j < 8; j++) ov[j] = (h16)facc[q * 8 + j];
        *(f16x8*)(sA + swz(r, cs * 2 + q * 16)) = ov;
      }
    }
    __syncthreads();  // bar1: sA ready

    // ---- K=256 MFMA: dense (regs) @ sB-Wr + agg (sA) @ sB-Wl
    f32x4 acc[4];
#pragma unroll
    for (int j = 0; j < 4; j++) acc[j] = (f32x4){0.f, 0.f, 0.f, 0.f};
    {
      f16x8 ads[4] = {ad0, ad1, ad2, ad3};
#pragma unroll
      for (int s = 0; s < 4; s++) {
#pragma unroll
        for (int j = 0; j < 4; j++) {
          int n = (cg * 4 + j) * 16 + lm;
          f16x8 b = *(const f16x8*)(sB + swzB(n, s * 64 + lk * 16));
          acc[j] = __builtin_amdgcn_mfma_f32_16x16x32_f16(ads[s], b, acc[j], 0, 0, 0);
        }
      }
#pragma unroll
      for (int s = 0; s < 4; s++) {
        f16x8 a = *(const f16x8*)(sA + swz(rg * 16 + lm, s * 64 + lk * 16));
#pragma unroll
        for (int j = 0; j < 4; j++) {
          int n = (cg * 4 + j) * 16 + lm;
          f16x8 b = *(const f16x8*)(sB + swzB(n, 256 + s * 64 + lk * 16));
          acc[j] = __builtin_amdgcn_mfma_f32_16x16x32_f16(a, b, acc[j], 0, 0, 0);
        }
      }
    }

    // ---- epilogue: folded bn + relu, direct stores to permuted rows
    int prowS[4];
#pragma unroll
    for (int r_ = 0; r_ < 4; r_++) {
      int pos = base + rg * 16 + lk * 4 + r_;
      prowS[r_] = (pos < M) ? perm[pos] : -1;
    }
#pragma unroll
    for (int j = 0; j < 4; j++) {
      int col = (cg * 4 + j) * 16 + lm;
#pragma unroll
      for (int r_ = 0; r_ < 4; r_++) {
        if (prowS[r_] >= 0) {
          float x = fmaf(acc[j][r_], scv[j], shv[j]);
          C[(size_t)prowS[r_] * Hv + col] = (h16)fmaxf(x, 0.f);
        }
      }
    }
    __syncthreads();  // bar2: sA reads done before next tile's gather writes
  }
}

// out = relu(h @ W1 + b1) @ W2 + b2, h = [h_u ; h_t] virtual concat
__global__ __launch_bounds__(512, 4) void k_mlp(const h16* __restrict__ HU,
                                                const h16* __restrict__ HT,
                                                const h16* __restrict__ W1T,
                                                const float* __restrict__ b1,
                                                const float* __restrict__ W2,
                                                const float* __restrict__ b2,
                                                float* __restrict__ out, int Mtot) {
  __shared__ float y[128][65];                       // 33280 B
  __shared__ __align__(16) unsigned char sW[64 * 256];  // 16 KB, swizzled
  int t = threadIdx.x;
  int w = t >> 6, l = t & 63;
  int lm = l & 15, lk = l >> 4;

  // stage W1T (8192 h16) coalesced: thread t owns 16 h16
  {
    const h16* src = W1T + t * 16;
    f16x8 w0 = *(const f16x8*)(src + 0);
    f16x8 w1 = *(const f16x8*)(src + 8);
    int n = (t * 16) >> 7;
    int kb = ((t * 16) & 127) * 2;
    *(f16x8*)(sW + swz(n, kb + 0)) = w0;
    *(f16x8*)(sW + swz(n, kb + 16)) = w1;
  }

  int rowBase = blockIdx.x * 128 + w * 16;
  int ar = imin(rowBase + lm, Mtot - 1);
  const h16* arow =
      (ar < NUv) ? (HU + (size_t)ar * Hv) : (HT + (size_t)(ar - NUv) * Hv);
  f16x8 a0 = *(const f16x8*)(arow + 0 * 32 + lk * 8);
  f16x8 a1 = *(const f16x8*)(arow + 1 * 32 + lk * 8);
  f16x8 a2 = *(const f16x8*)(arow + 2 * 32 + lk * 8);
  f16x8 a3 = *(const f16x8*)(arow + 3 * 32 + lk * 8);
  __syncthreads();

  f32x4 acc[4];
#pragma unroll
  for (int nf = 0; nf < 4; nf++) acc[nf] = (f32x4){0.f, 0.f, 0.f, 0.f};
  {
    f16x8 as[4] = {a0, a1, a2, a3};
#pragma unroll
    for (int s = 0; s < 4; s++) {
#pragma unroll
      for (int nf = 0; nf < 4; nf++) {
        f16x8 b = *(const f16x8*)(sW + swz(nf * 16 + lm, s * 64 + lk * 16));
        acc[nf] = __builtin_amdgcn_mfma_f32_16x16x32_f16(as[s], b, acc[nf], 0, 0, 0);
      }
    }
  }
#pragma unroll
  for (int nf = 0; nf < 4; nf++) {
    int col = nf * 16 + lm;
    float b1v = b1[col];
#pragma unroll
    for (int r = 0; r < 4; r++) {
      int rloc = w * 16 + lk * 4 + r;
      y[rloc][col] = fmaxf(acc[nf][r] + b1v, 0.f);
    }
  }
  __syncthreads();
  if (t < 256) {
    int rloc = t >> 1, o = t & 1;
    int row = blockIdx.x * 128 + rloc;
    if (row < Mtot) {
      float sum = b2[o];
#pragma unroll
      for (int k = 0; k < HID2v; k++) sum += y[rloc][k] * W2[k * 2 + o];
      out[(size_t)row * 2 + o] = sum;
    }
  }
}

// ---------------------------------------------------------------- launcher
extern "C" void kernel_launch(void* const* d_in, const int* in_sizes, int n_in,
                              void* d_out, int out_size, void* d_ws, size_t ws_size,
                              hipStream_t stream) {
  (void)in_sizes; (void)n_in; (void)out_size;

  const int* x_user  = (const int*)d_in[0];
  const int* x_txn   = (const int*)d_in[1];
  const int* ei0_src = (const int*)d_in[2];
  const int* ei0_dst = (const int*)d_in[3];
  const int* ei1_src = (const int*)d_in[4];
  const int* ei1_dst = (const int*)d_in[5];
  const float* emb_user = (const float*)d_in[6];
  const float* emb_txn  = (const float*)d_in[7];
  const float* Wl = (const float*)d_in[8];
  const float* bl = (const float*)d_in[9];
  const float* Wr = (const float*)d_in[10];
  const float* bn_g = (const float*)d_in[11];
  const float* bn_b = (const float*)d_in[12];
  const float* bn_m = (const float*)d_in[13];
  const float* bn_v = (const float*)d_in[14];
  const float* W1 = (const float*)d_in[15];
  const float* b1 = (const float*)d_in[16];
  const float* W2 = (const float*)d_in[17];
  const float* b2 = (const float*)d_in[18];
  float* out = (float*)d_out;

  char* wsb;
  if (ws_size >= (size_t)WS_NEED) {
    wsb = (char*)d_ws;
  } else {
    void* sym = nullptr;
    hipGetSymbolAddress(&sym, HIP_SYMBOL(g_ws));
    wsb = (char*)sym;
  }
  size_t o = 0;
  auto alloc = [&](size_t bytes) -> void* {
    o = (o + 255) & ~(size_t)255;
    void* p = wsb + o;
    o += bytes;
    return p;
  };
  h16* hu0  = (h16*)alloc((size_t)NUv * Hv * 2);   // ping-pong
  h16* hu1  = (h16*)alloc((size_t)NUv * Hv * 2);
  h16* ht0  = (h16*)alloc((size_t)NTv * Hv * 2);   // ping-pong
  h16* ht1  = (h16*)alloc((size_t)NTv * Hv * 2);
  h16* WlT  = (h16*)alloc((size_t)NLv * 2 * Hv * Hv * 2);
  h16* WrT  = (h16*)alloc((size_t)NLv * 2 * Hv * Hv * 2);
  h16* W1T  = (h16*)alloc((size_t)HID2v * Hv * 2);
  float* bnsc = (float*)alloc((size_t)NLv * 2 * Hv * 4);
  float* bnsh = (float*)alloc((size_t)NLv * 2 * Hv * 4);
  int* off0 = (int*)alloc((size_t)(NTv + 1) * 4);
  int* off1 = (int*)alloc((size_t)(NUv + 1) * 4);
  int* cur0 = (int*)alloc((size_t)NTv * 4);
  int* cur1 = (int*)alloc((size_t)NUv * 4);
  int* ss0  = (int*)alloc((size_t)Ev * 4);
  int* ss1  = (int*)alloc((size_t)Ev * 4);
  int* bs0  = (int*)alloc(256 * 4);
  int* bs1  = (int*)alloc(256 * 4);
  int* perm0 = (int*)alloc((size_t)NTv * 4);
  int* perm1 = (int*)alloc((size_t)NUv * 4);
  int* hist0 = (int*)alloc(32 * 4);
  int* hist1 = (int*)alloc(32 * 4);

  const int G_E    = (Ev + 255) / 256;
  const int G_BS0  = (NTv + 2047) / 2048;        // 196
  const int G_BS1  = (NUv + 2047) / 2048;        // 49
  const int G_R0   = (NTv + 255) / 256;          // 1563 (row-parallel, dir0)
  const int G_R1   = (NUv + 255) / 256;          // 391  (row-parallel, dir1)
  const int G_EMB  = ((NUv + NTv) * 16 + 255) / 256;
  const int N_WTBN = NLv * 2 * Hv * Hv + HID2v * Hv + NLv * 2 * Hv;
  const int G_WTBN = (N_WTBN + 255) / 256;
  const int G_F    = 512;                        // persistent grid
  const int G_MLP  = (NUv + NTv + 127) / 128;    // 3907

  // 1. CSR build
  hipMemsetAsync(cur0, 0, (size_t)NTv * 4, stream);
  hipMemsetAsync(cur1, 0, (size_t)NUv * 4, stream);
  hipMemsetAsync(hist0, 0, 32 * 4, stream);
  hipMemsetAsync(hist1, 0, 32 * 4, stream);
  k_count<<<G_E, 256, 0, stream>>>(ei0_dst, ei1_dst, cur0, cur1, Ev);
  k_blocksum2<<<G_BS0 + G_BS1, 256, 0, stream>>>(cur0, NTv, G_BS0, cur1, NUv,
                                                 bs0, bs1);
  k_scansmall2<<<2, 256, 0, stream>>>(bs0, G_BS0, bs1, G_BS1);
  k_scanfinal2<<<G_BS0 + G_BS1, 256, 0, stream>>>(cur0, NTv, G_BS0, bs0, off0,
                                                  cur0, cur1, NUv, bs1, off1,
                                                  cur1);
  k_fill<<<G_E, 256, 0, stream>>>(ei0_src, ei0_dst, ei1_src, ei1_dst,
                                  cur0, cur1, ss0, ss1, Ev);

  // 1b. degree counting sort -> perm (uniform-degree tiles)
  k_deghist2<<<G_R0 + G_R1, 256, 0, stream>>>(off0, NTv, G_R0, off1, NUv,
                                              hist0, hist1);
  k_degscan2<<<2, 64, 0, stream>>>(hist0, hist1);
  k_degscatter2<<<G_R0 + G_R1, 256, 0, stream>>>(off0, NTv, G_R0, off1, NUv,
                                                 hist0, hist1, perm0, perm1);

  // 2. weight conversion + bn prep
  k_wtbn<<<G_WTBN, 256, 0, stream>>>(Wl, Wr, W1, bn_g, bn_b, bn_m, bn_v,
                                     WlT, WrT, W1T, bnsc, bnsh);

  // 3. embedding gather
  k_embed<<<G_EMB, 256, 0, stream>>>(x_user, x_txn, emb_user, emb_txn, hu0, ht0);

  // 4. layers (r8 structure: separate T/U dispatches, ping-pong buffers)
  h16* hu_cur = hu0; h16* hu_nxt = hu1;
  h16* ht_cur = ht0; h16* ht_nxt = ht1;
  for (int i = 0; i < NLv; i++) {
    const h16* WlT0 = WlT + (size_t)(i * 2 + 0) * Hv * Hv;
    const h16* WlT1 = WlT + (size_t)(i * 2 + 1) * Hv * Hv;
    const h16* WrT0 = WrT + (size_t)(i * 2 + 0) * Hv * Hv;
    const h16* WrT1 = WrT + (size_t)(i * 2 + 1) * Hv * Hv;
    const float* bl0 = bl + (size_t)(i * 2 + 0) * Hv;
    const float* bl1 = bl + (size_t)(i * 2 + 1) * Hv;
    const float* sc0 = bnsc + (size_t)(i * 2 + 0) * Hv;
    const float* sh0 = bnsh + (size_t)(i * 2 + 0) * Hv;
    const float* sc1 = bnsc + (size_t)(i * 2 + 1) * Hv;
    const float* sh1 = bnsh + (size_t)(i * 2 + 1) * Hv;

    // h_t' : agg CSR0 (src=hu_cur), dense=ht_cur -> ht_nxt ; bn[i,1]
    k_fused<<<G_F, 512, 0, stream>>>(hu_cur, ht_cur, off0, ss0, perm0,
                                     WlT0, WrT0, bl0, sc1, sh1, ht_nxt, NTv);
    // h_u' : agg CSR1 (src=ht_cur OLD), dense=hu_cur -> hu_nxt ; bn[i,0]
    k_fused<<<G_F, 512, 0, stream>>>(ht_cur, hu_cur, off1, ss1, perm1,
                                     WlT1, WrT1, bl1, sc0, sh0, hu_nxt, NUv);
    h16* tmp;
    tmp = ht_cur; ht_cur = ht_nxt; ht_nxt = tmp;
    tmp = hu_cur; hu_cur = hu_nxt; hu_nxt = tmp;
  }

  // 5. MLP head
  k_mlp<<<G_MLP, 512, 0, stream>>>(hu_cur, ht_cur, W1T, b1, W2, b2, out,
                                   NUv + NTv);
}